// Round 6
// baseline (320.226 us; speedup 1.0000x reference)
//
#include <hip/hip_runtime.h>
#include <math.h>

#define BS 4
#define NCH 20
#define IMH 480
#define IMW 640
#define NPIX (IMH*IMW)           /* 307200 */
#define MSZ 480
#define MPX (MSZ*MSZ)            /* 230400 */
#define VR 100

#define TX 5
#define TY 8
#define NRX 20
#define NRY 13
#define NBIN (NRX*NRY)           /* 260 */
#define CELLS (TX*TY)            /* 40 */
#define CELLF 401                /* odd stride -> LDS bank spread; 64160 B -> 2 blocks/CU */

#define FPSCALE 65536.0f
#define FPINV   (1.0f/65536.0f)

static constexpr size_t SEG = (size_t)BS*NCH*MPX;
static constexpr size_t SEMT_FLOATS = (size_t)BS*NPIX*16;
static constexpr size_t LIST_OFF    = SEMT_FLOATS;
static_assert(SEMT_FLOATS < 2*SEG, "semT must fit in out0+out1 segments");

static constexpr size_t OFF_AV     = 0;            // BS*18*10000
static constexpr size_t OFF_AVS    = 720000;       // BS*10000
static constexpr size_t OFF_PAR    = 1681600;      // 64 floats
static constexpr size_t OFF_COUNTS = 1681664;      // 1040 uints
static constexpr size_t OFF_OFFS   = 1682704;
static constexpr size_t OFF_CURS   = 1683744;

__device__ __forceinline__ float clip01(float v) { return fminf(fmaxf(v, 0.0f), 1.0f); }

struct Geo { float px, py, pz; };

__device__ __forceinline__ Geo geom(int p, float depth, float F, float ca, float sa) {
  int j = p % IMW;
  int i = p / IMW;
  float dF = depth * (1.0f / F);
  float X  = ((float)j - 319.5f) * dF;
  X += 250.0f;
  float gz = (float)(IMH - 1 - i);
  float Zc = (gz - 239.5f) * dF;
  float Y  = ca*depth - sa*Zc;
  float Z  = sa*depth + ca*Zc + 88.0f;
  float xs = (X/5.0f - 50.0f)/100.0f*2.0f;
  float ys = (Y/5.0f - 50.0f)/100.0f*2.0f;
  float zs = (Z/5.0f - 16.0f)/48.0f*2.0f;
  Geo g;
  g.px = xs*50.0f + 50.0f;
  g.py = ys*50.0f + 50.0f;
  g.pz = zs*24.0f + 24.0f;
  return g;
}

__device__ __forceinline__ int pixel_bins(Geo g, int bins[4]) {
  float fx = floorf(g.px), fy = floorf(g.py), fz = floorf(g.pz);
  float fx1 = fx + 1.0f, fy1 = fy + 1.0f, fz1 = fz + 1.0f;
  bool vx0 = (fx  > 0.0f) && (fx  < 100.0f);
  bool vx1 = (fx1 > 0.0f) && (fx1 < 100.0f);
  bool vy0 = (fy  > 0.0f) && (fy  < 100.0f);
  bool vy1 = (fy1 > 0.0f) && (fy1 < 100.0f);
  bool vz0 = (fz  > 0.0f) && (fz  < 48.0f);
  bool vz1 = (fz1 > 0.0f) && (fz1 < 48.0f);
  if (!((vx0||vx1) && (vy0||vy1) && (vz0||vz1))) return 0;
  int rxs[2]; int nx = 0;
  if (vx0) rxs[nx++] = (int)fx / TX;
  if (vx1) { int r = (int)fx1 / TX; if (!nx || r != rxs[0]) rxs[nx++] = r; }
  int rys[2]; int ny = 0;
  if (vy0) rys[ny++] = (int)fy / TY;
  if (vy1) { int r = (int)fy1 / TY; if (!ny || r != rys[0]) rys[ny++] = r; }
  int n = 0;
  for (int a = 0; a < ny; ++a)
    for (int c = 0; c < nx; ++c)
      bins[n++] = rys[a]*NRX + rxs[c];
  return n;
}

// ---------------------------------------------------------------- pose (+ zero bin counts)
__global__ void k_pose(const float* __restrict__ pose_obs,
                       const float* __restrict__ poses_last,
                       const float* __restrict__ eve,
                       float* __restrict__ par,
                       float* __restrict__ out_poses,
                       unsigned* __restrict__ counts) {
  int b = threadIdx.x;
  for (int i = b; i < BS*NBIN; i += 64) counts[i] = 0u;
  if (b >= BS) return;
  const float R2Df = 57.29577951308232f;
  const float D2R  = 0.017453292519943295f;
  float pl0 = poses_last[b*3+0], pl1 = poses_last[b*3+1], pl2 = poses_last[b*3+2];
  float po0 = pose_obs[b*3+0],   po1 = pose_obs[b*3+1],   po2 = pose_obs[b*3+2];
  float r  = pl2 / R2Df;
  float sr = sinf(r), cr = cosf(r);
  float ny = pl1 + po0*sr + po1*cr;
  float nx = pl0 + po0*cr - po1*sr;
  float nt = pl2 + po2*R2Df;
  nt = fmodf(nt - 180.0f, 360.0f) + 180.0f;
  nt = fmodf(nt + 180.0f, 360.0f) - 180.0f;
  out_poses[b*3+0] = nx;
  out_poses[b*3+1] = ny;
  out_poses[b*3+2] = nt;
  float a = eve[b] * D2R;
  par[b*8+0] = cosf(a);
  par[b*8+1] = sinf(a);
  float t = (90.0f - nt) * D2R;
  par[b*8+2] = cosf(t);
  par[b*8+3] = sinf(t);
  par[b*8+4] = (240.0f - nx*100.0f/5.0f) / 240.0f;
  par[b*8+5] = (240.0f - ny*100.0f/5.0f) / 240.0f;
  par[b*8+6] = (eve[b] == 0.0f) ? 1.0f : 0.0f;
  if (b == 0) {
    int sxi = (int)(nx * 100.0f / 5.0f);
    int syi = (int)(ny * 100.0f / 5.0f);
    sxi = min(max(sxi, 30), 449);
    syi = min(max(syi, 30), 449);
    par[32] = (float)sxi;
    par[33] = (float)syi;
    par[34] = (float)(320.0 / tan(39.5 * 0.017453292519943295));
  }
}

// ---------------------------------------------------------------- prep: sem transpose + bin count (one pass)
__global__ __launch_bounds__(256) void k_prep(const float* __restrict__ obs,
                                              const float* __restrict__ par,
                                              unsigned* __restrict__ counts,
                                              float* __restrict__ semT) {
  __shared__ unsigned hist[NBIN];
  int tid = threadIdx.x;
  int b   = blockIdx.y;
  for (int i = tid; i < NBIN; i += 256) hist[i] = 0u;
  __syncthreads();
  const float F = par[34], ca = par[b*8+0], sa = par[b*8+1];
  const float* __restrict__ dpl  = obs + ((size_t)b*NCH + 3)*NPIX;
  const float* __restrict__ semb = obs + ((size_t)b*NCH + 4)*NPIX;
  int base = blockIdx.x * 2048;
#pragma unroll
  for (int k = 0; k < 8; ++k) {
    int p = base + k*256 + tid;
    float s[16];
#pragma unroll
    for (int c = 0; c < 16; ++c) s[c] = semb[(size_t)c*NPIX + p];
    float4* dst = (float4*)(semT + ((size_t)b*NPIX + p)*16);
    dst[0] = make_float4(s[0],  s[1],  s[2],  s[3]);
    dst[1] = make_float4(s[4],  s[5],  s[6],  s[7]);
    dst[2] = make_float4(s[8],  s[9],  s[10], s[11]);
    dst[3] = make_float4(s[12], s[13], s[14], s[15]);
    Geo g = geom(p, dpl[p], F, ca, sa);
    int bins[4];
    int n = pixel_bins(g, bins);
    for (int t = 0; t < n; ++t) atomicAdd(&hist[bins[t]], 1u);
  }
  __syncthreads();
  for (int i = tid; i < NBIN; i += 256) {
    unsigned v = hist[i];
    if (v) atomicAdd(&counts[b*NBIN + i], v);
  }
}

// ---------------------------------------------------------------- exclusive scan of BS*NBIN=1040 counts
__global__ __launch_bounds__(1024) void k_scan(const unsigned* __restrict__ counts,
                                               unsigned* __restrict__ offs,
                                               unsigned* __restrict__ curs) {
  __shared__ unsigned s[1024];
  int t = threadIdx.x;
  const int n2 = BS*NBIN;
  unsigned a  = (2*t   < n2) ? counts[2*t]   : 0u;
  unsigned bb = (2*t+1 < n2) ? counts[2*t+1] : 0u;
  unsigned pr = a + bb;
  s[t] = pr;
  __syncthreads();
  for (int off = 1; off < 1024; off <<= 1) {
    unsigned v = (t >= off) ? s[t - off] : 0u;
    __syncthreads();
    s[t] += v;
    __syncthreads();
  }
  unsigned excl = s[t] - pr;
  if (2*t < n2)   { offs[2*t]   = excl;     curs[2*t]   = excl;     }
  if (2*t+1 < n2) { offs[2*t+1] = excl + a; curs[2*t+1] = excl + a; }
}

// ---------------------------------------------------------------- scatter pixel ids into bin lists
__global__ __launch_bounds__(256) void k_scatter(const float* __restrict__ obs,
                                                 const float* __restrict__ par,
                                                 unsigned* __restrict__ curs,
                                                 unsigned* __restrict__ list) {
  __shared__ unsigned hist[NBIN];
  __shared__ unsigned lbase[NBIN];
  __shared__ unsigned slot[NBIN];
  int tid = threadIdx.x;
  int b   = blockIdx.y;
  for (int i = tid; i < NBIN; i += 256) { hist[i] = 0u; slot[i] = 0u; }
  __syncthreads();
  const float F = par[34], ca = par[b*8+0], sa = par[b*8+1];
  const float* __restrict__ dpl = obs + ((size_t)b*NCH + 3)*NPIX;
  int base = blockIdx.x * 2048;
#pragma unroll
  for (int k = 0; k < 8; ++k) {
    int p = base + k*256 + tid;
    Geo g = geom(p, dpl[p], F, ca, sa);
    int bins[4];
    int n = pixel_bins(g, bins);
    for (int t = 0; t < n; ++t) atomicAdd(&hist[bins[t]], 1u);
  }
  __syncthreads();
  for (int i = tid; i < NBIN; i += 256) {
    unsigned h = hist[i];
    lbase[i] = h ? atomicAdd(&curs[b*NBIN + i], h) : 0u;
  }
  __syncthreads();
#pragma unroll
  for (int k = 0; k < 8; ++k) {
    int p = base + k*256 + tid;
    Geo g = geom(p, dpl[p], F, ca, sa);
    int bins[4];
    int n = pixel_bins(g, bins);
    for (int t = 0; t < n; ++t) {
      int bn = bins[t];
      unsigned sidx = atomicAdd(&slot[bn], 1u);
      list[lbase[bn] + sidx] = (unsigned)p;
    }
  }
}

// ---------------------------------------------------------------- splat + reduce (list-driven, u32 fixed-point LDS)
__global__ __launch_bounds__(1024) void k_splat2(const float* __restrict__ obs,
                                                 const float* __restrict__ semT,
                                                 const float* __restrict__ par,
                                                 const unsigned* __restrict__ offs,
                                                 const unsigned* __restrict__ counts,
                                                 const unsigned* __restrict__ list,
                                                 float* __restrict__ av,
                                                 float* __restrict__ avs) {
  __shared__ unsigned lds[CELLS * CELLF];
  const int tid = threadIdx.x;
  const int reg = blockIdx.x;
  const int b   = blockIdx.y;
  const int rx0 = (reg % NRX) * TX;
  const int ry0 = (reg / NRX) * TY;

  for (int i = tid; i < CELLS * CELLF; i += 1024) lds[i] = 0u;
  __syncthreads();

  const float F = par[34], ca = par[b*8+0], sa = par[b*8+1];
  const float* __restrict__ dpl = obs + ((size_t)b*NCH + 3)*NPIX;

  const unsigned bin   = (unsigned)b*NBIN + reg;
  const unsigned start = offs[bin];
  const unsigned n     = counts[bin];

  for (unsigned ii = tid; ii < n; ii += 1024) {
    int p = (int)list[start + ii];
    Geo g = geom(p, dpl[p], F, ca, sa);
    float px = g.px, py = g.py, pz = g.pz;
    float fx = floorf(px), fy = floorf(py), fz = floorf(pz);

    float wxa[2], wya[2], wza[2];
    int   ixa[2], iya[2], iza[2];
    bool  vx[2], vy[2], vz[2];
#pragma unroll
    for (int k = 0; k < 2; ++k) {
      float pv = fx + (float)k;
      bool sg = (pv > 0.0f) && (pv < 100.0f);
      wxa[k] = sg ? (1.0f - fabsf(px - pv)) : 0.0f;
      ixa[k] = (int)pv;
      vx[k]  = sg && (ixa[k] >= rx0) && (ixa[k] < rx0 + TX);

      pv = fy + (float)k;
      sg = (pv > 0.0f) && (pv < 100.0f);
      wya[k] = sg ? (1.0f - fabsf(py - pv)) : 0.0f;
      iya[k] = (int)pv;
      vy[k]  = sg && (iya[k] >= ry0) && (iya[k] < ry0 + TY);

      pv = fz + (float)k;
      sg = (pv > 0.0f) && (pv < 48.0f);
      wza[k] = sg ? (1.0f - fabsf(pz - pv)) : 0.0f;
      iza[k] = (int)pv;
      vz[k]  = sg;
    }

    bool needSem = false;
#pragma unroll
    for (int k = 0; k < 2; ++k)
      if (vz[k] && iza[k] >= 13 && iza[k] < 35 && wza[k] != 0.0f) needSem = true;

    float sem[16];
    if (needSem) {
      const float4* sp = (const float4*)(semT + ((size_t)b*NPIX + p)*16);
      float4 s0 = sp[0], s1 = sp[1], s2 = sp[2], s3 = sp[3];
      sem[0]=s0.x; sem[1]=s0.y; sem[2]=s0.z; sem[3]=s0.w;
      sem[4]=s1.x; sem[5]=s1.y; sem[6]=s1.z; sem[7]=s1.w;
      sem[8]=s2.x; sem[9]=s2.y; sem[10]=s2.z; sem[11]=s2.w;
      sem[12]=s3.x; sem[13]=s3.y; sem[14]=s3.z; sem[15]=s3.w;
    }

#pragma unroll
    for (int cx = 0; cx < 2; ++cx) {
      if (!vx[cx] || wxa[cx] == 0.0f) continue;
#pragma unroll
      for (int cy = 0; cy < 2; ++cy) {
        if (!vy[cy]) continue;
        float wxy = wxa[cx] * wya[cy];
        if (wxy == 0.0f) continue;
        unsigned* cellp = lds + (size_t)((ixa[cx]-rx0)*TY + (iya[cy]-ry0)) * CELLF;
#pragma unroll
        for (int cz = 0; cz < 2; ++cz) {
          if (!vz[cz]) continue;
          float wv = wxy * wza[cz];
          if (wv == 0.0f) continue;
          int zv = iza[cz];
          atomicAdd(cellp + zv, (unsigned)(wv*FPSCALE + 0.5f));
          if (zv >= 13 && zv < 35) {
            unsigned* p2 = cellp + 48 + (zv - 13)*16;
#pragma unroll
            for (int c = 0; c < 16; ++c)
              atomicAdd(p2 + c, (unsigned)(wv*sem[c]*FPSCALE + 0.5f));
          }
        }
      }
    }
  }
  __syncthreads();

  for (int it = tid; it < CELLS * 17; it += 1024) {
    int cell = it % CELLS;
    int ch   = it / CELLS;
    int lx = cell / TY, ly = cell % TY;
    int x = rx0 + lx, y = ry0 + ly;
    if (y >= 100) continue;
    size_t pxo = (size_t)y*VR + x;
    size_t ab  = (size_t)b*18*10000;
    const unsigned* cellp = lds + (size_t)cell * CELLF;
    if (ch == 0) {
      float all0 = 0.0f, ahp0 = 0.0f, asp0 = 0.0f;
#pragma unroll
      for (int z = 0; z < 48; ++z) {
        float v = rintf((float)cellp[z] * FPINV);
        all0 += v;
        if (z >= 13 && z < 35) ahp0 += v;
        if (z >= 20 && z < 25) asp0 += v;
      }
      av[ab + 0*10000 + pxo] = clip01(ahp0);
      av[ab + 1*10000 + pxo] = clip01(all0);
      avs[(size_t)b*10000 + pxo] = clip01(asp0);
    } else {
      int c = ch - 1;
      float acc = 0.0f;
      for (int z = 0; z < 22; ++z) acc += rintf((float)cellp[48 + z*16 + c] * FPINV);
      av[ab + (size_t)(2 + c)*10000 + pxo] = clip01(acc / 5.0f);
    }
  }
}

// ---------------------------------------------------------------- fused rot+trans+maxpool+merge
// translated(p) = sum_i w_i * rotsample(r_i) over p's 4 integer trans-neighbors r_i.
// Exact: the second grid_sample only evaluates the rotated image at integer grid points.
// SAFETY: every tap carries its own in-bounds offset (0 when invalid); zero weight
// nullifies the (safe) read. Weight-zero alone does NOT make a load safe (round-5 fault).
struct Nb { float wt, w00, w10, w01, w11; int o00, o10, o01, o11; };

__device__ __forceinline__ Nb rot_taps(int xi, int yi, float ct, float st, float wt) {
  Nb nb; nb.wt = 0.0f;
  nb.w00 = nb.w10 = nb.w01 = nb.w11 = 0.0f;
  nb.o00 = nb.o10 = nb.o01 = nb.o11 = 0;
  if (xi < 0 || xi >= MSZ || yi < 0 || yi >= MSZ) return nb;
  float gx = ((xi + 0.5f)*2.0f)/480.0f - 1.0f;
  float gy = ((yi + 0.5f)*2.0f)/480.0f - 1.0f;
  float u = gx*ct - gy*st;
  float v = gx*st + gy*ct;
  float xf = (u + 1.0f)*0.5f*479.0f;
  float yf = (v + 1.0f)*0.5f*479.0f;
  float x0f = floorf(xf), y0f = floorf(yf);
  int x0 = (int)x0f, y0 = (int)y0f;
  if (x0 < 189 || x0 > 289 || y0 < 239 || y0 > 339) return nb;
  float wx = xf - x0f, wy = yf - y0f;
  bool vx0 = (x0   >= 190) && (x0   < 290);
  bool vx1 = (x0+1 >= 190) && (x0+1 < 290);
  bool vy0 = (y0   >= 240) && (y0   < 340);
  bool vy1 = (y0+1 >= 240) && (y0+1 < 340);
  int base = (y0-240)*100 + (x0-190);
  bool v00 = vx0&&vy0, v10 = vx1&&vy0, v01 = vx0&&vy1, v11 = vx1&&vy1;
  nb.w00 = v00 ? (1.0f-wx)*(1.0f-wy) : 0.0f;  nb.o00 = v00 ? base       : 0;
  nb.w10 = v10 ? wx*(1.0f-wy)        : 0.0f;  nb.o10 = v10 ? base + 1   : 0;
  nb.w01 = v01 ? (1.0f-wx)*wy        : 0.0f;  nb.o01 = v01 ? base + 100 : 0;
  nb.w11 = v11 ? wx*wy               : 0.0f;  nb.o11 = v11 ? base + 101 : 0;
  nb.wt  = wt;
  return nb;
}

__device__ __forceinline__ bool trans_nbs(int w, int h, float sx, float sy,
                                          float ct, float st, Nb nb[4]) {
#pragma unroll
  for (int i = 0; i < 4; ++i) {
    nb[i].wt = 0.0f;
    nb[i].w00 = nb[i].w10 = nb[i].w01 = nb[i].w11 = 0.0f;
    nb[i].o00 = nb[i].o10 = nb[i].o01 = nb[i].o11 = 0;
  }
  float gx = ((w + 0.5f)*2.0f)/480.0f - 1.0f;
  float gy = ((h + 0.5f)*2.0f)/480.0f - 1.0f;
  float xf = ((gx + sx) + 1.0f)*0.5f*479.0f;
  float yf = ((gy + sy) + 1.0f)*0.5f*479.0f;
  float x0f = floorf(xf), y0f = floorf(yf);
  int x0 = (int)x0f, y0 = (int)y0f;
  if (x0 < -1 || x0 > 479 || y0 < -1 || y0 > 479) return false;
  float wx = xf - x0f, wy = yf - y0f;
  nb[0] = rot_taps(x0,   y0,   ct, st, (1.0f-wx)*(1.0f-wy));
  nb[1] = rot_taps(x0+1, y0,   ct, st, wx*(1.0f-wy));
  nb[2] = rot_taps(x0,   y0+1, ct, st, (1.0f-wx)*wy);
  nb[3] = rot_taps(x0+1, y0+1, ct, st, wx*wy);
  return (nb[0].wt!=0.0f)||(nb[1].wt!=0.0f)||(nb[2].wt!=0.0f)||(nb[3].wt!=0.0f);
}

__device__ __forceinline__ float eval_plane(const float* __restrict__ plane, const Nb nb[4]) {
  float t = 0.0f;
#pragma unroll
  for (int i = 0; i < 4; ++i) {
    if (nb[i].wt == 0.0f) continue;
    float r = plane[nb[i].o00]*nb[i].w00 + plane[nb[i].o10]*nb[i].w10
            + plane[nb[i].o01]*nb[i].w01 + plane[nb[i].o11]*nb[i].w11;
    t += nb[i].wt * r;
  }
  return t;
}

#define TILE 16
__global__ __launch_bounds__(256) void k_fused(const float* __restrict__ av,
                                               const float* __restrict__ avs,
                                               const float* __restrict__ par,
                                               const float* __restrict__ maps_last,
                                               float* __restrict__ out0,
                                               float* __restrict__ out1,
                                               float* __restrict__ out2) {
  __shared__ float t0s[18][19];
  const int b   = blockIdx.y;
  const int tx0 = (blockIdx.x % (MSZ/TILE)) * TILE;
  const int ty0 = (blockIdx.x / (MSZ/TILE)) * TILE;
  const int lx  = threadIdx.x % TILE;
  const int ly  = threadIdx.x / TILE;

  const float ct = par[b*8+2], st = par[b*8+3];
  const float sx = par[b*8+4], sy = par[b*8+5];
  const float* __restrict__ av0 = av + (size_t)b*18*10000;

  // phase 1: fused ch0 for 18x18 halo
  for (int q = threadIdx.x; q < 18*18; q += 256) {
    int hy = q / 18, hx = q % 18;
    int h = ty0 + hy - 1, w = tx0 + hx - 1;
    float v;
    if (h < 0 || h >= MSZ || w < 0 || w >= MSZ) {
      v = -INFINITY;
    } else {
      Nb nb[4];
      v = trans_nbs(w, h, sx, sy, ct, st, nb) ? eval_plane(av0, nb) : 0.0f;
    }
    t0s[hy][hx] = v;
  }
  __syncthreads();

  // phase 2: own pixel
  const int h = ty0 + ly, w = tx0 + lx;
  const size_t pix = (size_t)h*MSZ + w;

  float mp = -INFINITY;
#pragma unroll
  for (int dy = 0; dy < 3; ++dy)
#pragma unroll
    for (int dx = 0; dx < 3; ++dx)
      mp = fmaxf(mp, t0s[ly+dy][lx+dx]);
  float t0 = t0s[ly+1][lx+1];

  Nb nb[4];
  bool hit = trans_nbs(w, h, sx, sy, ct, st, nb);

  float t[19];
  t[0] = t0;
  if (hit) {
#pragma unroll
    for (int s = 1; s < 18; ++s) t[s] = eval_plane(av0 + (size_t)s*10000, nb);
    t[18] = eval_plane(avs + (size_t)b*10000, nb);
  } else {
#pragma unroll
    for (int s = 1; s < 19; ++s) t[s] = 0.0f;
  }

  float t1v = t[1];
  bool eve0 = (par[b*8+6] != 0.0f);
  bool kill = ((t1v - mp) > 0.8f) && eve0;

  float sg = 1.0f;
  if (b == 0) {
    int sxi = (int)par[32], syi = (int)par[33];
    int di = h - (syi - 30);
    int dj = w - (sxi - 30);
    if (di >= 0 && di < 60 && dj >= 0 && dj < 60) {
      float aa = (float)di - 29.5f;
      float bb = (float)dj - 29.5f;
      sg = (aa*aa + bb*bb <= 900.0f) ? 1.0f : 0.0f;
    } else {
      sg = 0.0f;
    }
  }
  float tsv0 = t[18] * sg;
  float ts1  = t1v * sg;
  bool kill_s = ((ts1 - tsv0) > 0.8f) && eve0;

  const float* ML = maps_last + (size_t)b*NCH*MPX;
  float* O0 = out0 + (size_t)b*NCH*MPX;
  float* O1 = out1 + (size_t)b*NCH*MPX;
  float* O2 = out2 + (size_t)b*NCH*MPX;

#pragma unroll
  for (int c = 0; c < NCH; ++c) {
    float tv  = (c == 0) ? t0 : ((c == 1) ? t1v : ((c < 4) ? 0.0f : t[c - 2]));
    float tsv = (c == 0) ? tsv0 : ((c == 1) ? ts1 : tv);
    float ml  = ML[(size_t)c*MPX + pix];
    float mpv = fmaxf(ml, tv);
    float msv = fmaxf(ml, tsv);
    if (c == 0) {
      if (kill)   mpv = 0.0f;
      if (kill_s) msv = 0.0f;
    }
    O0[(size_t)c*MPX + pix] = tv;
    O1[(size_t)c*MPX + pix] = mpv;
    O2[(size_t)c*MPX + pix] = msv;
  }
}

// ---------------------------------------------------------------- launch
extern "C" void kernel_launch(void* const* d_in, const int* in_sizes, int n_in,
                              void* d_out, int out_size, void* d_ws, size_t ws_size,
                              hipStream_t stream) {
  (void)in_sizes; (void)n_in; (void)out_size; (void)ws_size;
  const float* obs        = (const float*)d_in[0];
  const float* pose_obs   = (const float*)d_in[1];
  const float* maps_last  = (const float*)d_in[2];
  const float* poses_last = (const float*)d_in[3];
  const float* eve        = (const float*)d_in[4];
  float* out = (float*)d_out;
  float* ws  = (float*)d_ws;

  float*    av     = ws + OFF_AV;
  float*    avs    = ws + OFF_AVS;
  float*    par    = ws + OFF_PAR;
  unsigned* counts = (unsigned*)(ws + OFF_COUNTS);
  unsigned* offs   = (unsigned*)(ws + OFF_OFFS);
  unsigned* curs   = (unsigned*)(ws + OFF_CURS);

  float* out0 = out;
  float* out1 = out + SEG;
  float* out2 = out + 2*SEG;
  float* outp = out + 3*SEG;

  // dead-segment scratch (all consumed before k_fused writes the outputs):
  float*    semT = out0;                        // spans out0 + head of out1
  unsigned* list = (unsigned*)(out + LIST_OFF); // inside out1 segment

  k_pose<<<1, 64, 0, stream>>>(pose_obs, poses_last, eve, par, outp, counts);
  {
    dim3 g(NPIX/2048, BS);
    k_prep<<<g, 256, 0, stream>>>(obs, par, counts, semT);
    k_scan<<<1, 1024, 0, stream>>>(counts, offs, curs);
    k_scatter<<<g, 256, 0, stream>>>(obs, par, curs, list);
  }
  {
    dim3 g(NBIN, BS);
    k_splat2<<<g, 1024, 0, stream>>>(obs, semT, par, offs, counts, list, av, avs);
  }
  {
    dim3 g((MSZ/TILE)*(MSZ/TILE), BS);
    k_fused<<<g, 256, 0, stream>>>(av, avs, par, maps_last, out0, out1, out2);
  }
}

// Round 7
// 288.290 us; speedup vs baseline: 1.1108x; 1.1108x over previous
//
#include <hip/hip_runtime.h>
#include <math.h>

#define BS 4
#define NCH 20
#define IMH 480
#define IMW 640
#define NPIX (IMH*IMW)           /* 307200 */
#define MSZ 480
#define MPX (MSZ*MSZ)            /* 230400 */
#define VR 100

#define TX 5
#define TY 8
#define NRX 20
#define NRY 13
#define NBIN (NRX*NRY)           /* 260 */
#define CELLS (TX*TY)            /* 40 */
#define CELLF 401                /* odd stride -> LDS bank spread; 64160 B -> 2 blocks/CU */

#define WND 176                  /* heavy-pass window (>= 152 worst-case) */
#define NT  11                   /* WND/16 */

#define FPSCALE 65536.0f
#define FPINV   (1.0f/65536.0f)

static constexpr size_t SEG = (size_t)BS*NCH*MPX;
static constexpr size_t SEMT_FLOATS = (size_t)BS*NPIX*16;
static constexpr size_t LIST_OFF    = SEMT_FLOATS;
static_assert(SEMT_FLOATS < 2*SEG, "semT must fit in out0+out1 segments");

static constexpr size_t OFF_AV     = 0;            // BS*18*10000
static constexpr size_t OFF_AVS    = 720000;       // BS*10000
static constexpr size_t OFF_PAR    = 1681600;      // 64 floats
static constexpr size_t OFF_COUNTS = 1681664;      // 1040 uints
static constexpr size_t OFF_OFFS   = 1682704;
static constexpr size_t OFF_CURS   = 1683744;

__device__ __forceinline__ float clip01(float v) { return fminf(fmaxf(v, 0.0f), 1.0f); }

struct Geo { float px, py, pz; };

__device__ __forceinline__ Geo geom(int p, float depth, float F, float ca, float sa) {
  int j = p % IMW;
  int i = p / IMW;
  float dF = depth * (1.0f / F);
  float X  = ((float)j - 319.5f) * dF;
  X += 250.0f;
  float gz = (float)(IMH - 1 - i);
  float Zc = (gz - 239.5f) * dF;
  float Y  = ca*depth - sa*Zc;
  float Z  = sa*depth + ca*Zc + 88.0f;
  float xs = (X/5.0f - 50.0f)/100.0f*2.0f;
  float ys = (Y/5.0f - 50.0f)/100.0f*2.0f;
  float zs = (Z/5.0f - 16.0f)/48.0f*2.0f;
  Geo g;
  g.px = xs*50.0f + 50.0f;
  g.py = ys*50.0f + 50.0f;
  g.pz = zs*24.0f + 24.0f;
  return g;
}

__device__ __forceinline__ int pixel_bins(Geo g, int bins[4]) {
  float fx = floorf(g.px), fy = floorf(g.py), fz = floorf(g.pz);
  float fx1 = fx + 1.0f, fy1 = fy + 1.0f, fz1 = fz + 1.0f;
  bool vx0 = (fx  > 0.0f) && (fx  < 100.0f);
  bool vx1 = (fx1 > 0.0f) && (fx1 < 100.0f);
  bool vy0 = (fy  > 0.0f) && (fy  < 100.0f);
  bool vy1 = (fy1 > 0.0f) && (fy1 < 100.0f);
  bool vz0 = (fz  > 0.0f) && (fz  < 48.0f);
  bool vz1 = (fz1 > 0.0f) && (fz1 < 48.0f);
  if (!((vx0||vx1) && (vy0||vy1) && (vz0||vz1))) return 0;
  int rxs[2]; int nx = 0;
  if (vx0) rxs[nx++] = (int)fx / TX;
  if (vx1) { int r = (int)fx1 / TX; if (!nx || r != rxs[0]) rxs[nx++] = r; }
  int rys[2]; int ny = 0;
  if (vy0) rys[ny++] = (int)fy / TY;
  if (vy1) { int r = (int)fy1 / TY; if (!ny || r != rys[0]) rys[ny++] = r; }
  int n = 0;
  for (int a = 0; a < ny; ++a)
    for (int c = 0; c < nx; ++c)
      bins[n++] = rys[a]*NRX + rxs[c];
  return n;
}

// ---------------------------------------------------------------- pose (+ zero bin counts + heavy window)
__global__ void k_pose(const float* __restrict__ pose_obs,
                       const float* __restrict__ poses_last,
                       const float* __restrict__ eve,
                       float* __restrict__ par,
                       float* __restrict__ out_poses,
                       unsigned* __restrict__ counts) {
  int b = threadIdx.x;
  for (int i = b; i < BS*NBIN; i += 64) counts[i] = 0u;
  if (b >= BS) return;
  const float R2Df = 57.29577951308232f;
  const float D2R  = 0.017453292519943295f;
  float pl0 = poses_last[b*3+0], pl1 = poses_last[b*3+1], pl2 = poses_last[b*3+2];
  float po0 = pose_obs[b*3+0],   po1 = pose_obs[b*3+1],   po2 = pose_obs[b*3+2];
  float r  = pl2 / R2Df;
  float sr = sinf(r), cr = cosf(r);
  float ny = pl1 + po0*sr + po1*cr;
  float nx = pl0 + po0*cr - po1*sr;
  float nt = pl2 + po2*R2Df;
  nt = fmodf(nt - 180.0f, 360.0f) + 180.0f;
  nt = fmodf(nt + 180.0f, 360.0f) - 180.0f;
  out_poses[b*3+0] = nx;
  out_poses[b*3+1] = ny;
  out_poses[b*3+2] = nt;
  float a = eve[b] * D2R;
  par[b*8+0] = cosf(a);
  par[b*8+1] = sinf(a);
  float t = (90.0f - nt) * D2R;
  float ct = cosf(t), st = sinf(t);
  float sxv = (240.0f - nx*100.0f/5.0f) / 240.0f;
  float syv = (240.0f - ny*100.0f/5.0f) / 240.0f;
  par[b*8+2] = ct;
  par[b*8+3] = st;
  par[b*8+4] = sxv;
  par[b*8+5] = syv;
  par[b*8+6] = (eve[b] == 0.0f) ? 1.0f : 0.0f;
  if (b == 0) {
    int sxi = (int)(nx * 100.0f / 5.0f);
    int syi = (int)(ny * 100.0f / 5.0f);
    sxi = min(max(sxi, 30), 449);
    syi = min(max(syi, 30), 449);
    par[32] = (float)sxi;
    par[33] = (float)syi;
    par[34] = (float)(320.0 / tan(39.5 * 0.017453292519943295));
  }
  // heavy-pass window: map AV rect corners through inverse rot, then inverse trans
  {
    const float u_lo = 189.0f/239.5f - 1.0f, u_hi = 290.0f/239.5f - 1.0f;
    const float v_lo = 239.0f/239.5f - 1.0f, v_hi = 340.0f/239.5f - 1.0f;
    float ximin = 1e9f, ximax = -1e9f, yimin = 1e9f, yimax = -1e9f;
#pragma unroll
    for (int k = 0; k < 4; ++k) {
      float uu = (k & 1) ? u_hi : u_lo;
      float vv = (k & 2) ? v_hi : v_lo;
      float gxc =  uu*ct + vv*st;       // inverse rotation
      float gyc = -uu*st + vv*ct;
      float xi = (gxc + 1.0f)*240.0f - 0.5f;
      float yi = (gyc + 1.0f)*240.0f - 0.5f;
      ximin = fminf(ximin, xi); ximax = fmaxf(ximax, xi);
      yimin = fminf(yimin, yi); yimax = fmaxf(yimax, yi);
    }
    float wmin = 240.0f*((ximin - 1.0f)/239.5f - sxv) - 0.5f;
    float hmin = 240.0f*((yimin - 1.0f)/239.5f - syv) - 0.5f;
    int wx0 = (int)floorf(wmin) - 3;
    int wy0 = (int)floorf(hmin) - 3;
    wx0 = min(max(wx0, 0), MSZ - WND);
    wy0 = min(max(wy0, 0), MSZ - WND);
    par[40 + b*2]     = (float)wx0;
    par[40 + b*2 + 1] = (float)wy0;
  }
}

// ---------------------------------------------------------------- prep: bin count + predicated sem transpose
__global__ __launch_bounds__(256) void k_prep(const float* __restrict__ obs,
                                              const float* __restrict__ par,
                                              unsigned* __restrict__ counts,
                                              float* __restrict__ semT) {
  __shared__ unsigned hist[NBIN];
  int tid = threadIdx.x;
  int b   = blockIdx.y;
  for (int i = tid; i < NBIN; i += 256) hist[i] = 0u;
  __syncthreads();
  const float F = par[34], ca = par[b*8+0], sa = par[b*8+1];
  const float* __restrict__ dpl  = obs + ((size_t)b*NCH + 3)*NPIX;
  const float* __restrict__ semb = obs + ((size_t)b*NCH + 4)*NPIX;
  int base = blockIdx.x * 2048;
#pragma unroll
  for (int k = 0; k < 8; ++k) {
    int p = base + k*256 + tid;
    Geo g = geom(p, dpl[p], F, ca, sa);
    int bins[4];
    int n = pixel_bins(g, bins);
    for (int t = 0; t < n; ++t) atomicAdd(&hist[bins[t]], 1u);
    // write semT only if this pixel can ever contribute sem (superset of splat2's needSem)
    bool wantSem = false;
    if (n > 0) {
      float fz = floorf(g.pz);
#pragma unroll
      for (int kk = 0; kk < 2; ++kk) {
        float pv = fz + (float)kk;
        if (pv > 0.0f && pv < 48.0f) {
          int zv = (int)pv;
          if (zv >= 13 && zv < 35) wantSem = true;
        }
      }
    }
    if (wantSem) {
      float s[16];
#pragma unroll
      for (int c = 0; c < 16; ++c) s[c] = semb[(size_t)c*NPIX + p];
      float4* dst = (float4*)(semT + ((size_t)b*NPIX + p)*16);
      dst[0] = make_float4(s[0],  s[1],  s[2],  s[3]);
      dst[1] = make_float4(s[4],  s[5],  s[6],  s[7]);
      dst[2] = make_float4(s[8],  s[9],  s[10], s[11]);
      dst[3] = make_float4(s[12], s[13], s[14], s[15]);
    }
  }
  __syncthreads();
  for (int i = tid; i < NBIN; i += 256) {
    unsigned v = hist[i];
    if (v) atomicAdd(&counts[b*NBIN + i], v);
  }
}

// ---------------------------------------------------------------- exclusive scan of BS*NBIN=1040 counts
__global__ __launch_bounds__(1024) void k_scan(const unsigned* __restrict__ counts,
                                               unsigned* __restrict__ offs,
                                               unsigned* __restrict__ curs) {
  __shared__ unsigned s[1024];
  int t = threadIdx.x;
  const int n2 = BS*NBIN;
  unsigned a  = (2*t   < n2) ? counts[2*t]   : 0u;
  unsigned bb = (2*t+1 < n2) ? counts[2*t+1] : 0u;
  unsigned pr = a + bb;
  s[t] = pr;
  __syncthreads();
  for (int off = 1; off < 1024; off <<= 1) {
    unsigned v = (t >= off) ? s[t - off] : 0u;
    __syncthreads();
    s[t] += v;
    __syncthreads();
  }
  unsigned excl = s[t] - pr;
  if (2*t < n2)   { offs[2*t]   = excl;     curs[2*t]   = excl;     }
  if (2*t+1 < n2) { offs[2*t+1] = excl + a; curs[2*t+1] = excl + a; }
}

// ---------------------------------------------------------------- scatter pixel ids into bin lists
__global__ __launch_bounds__(256) void k_scatter(const float* __restrict__ obs,
                                                 const float* __restrict__ par,
                                                 unsigned* __restrict__ curs,
                                                 unsigned* __restrict__ list) {
  __shared__ unsigned hist[NBIN];
  __shared__ unsigned lbase[NBIN];
  __shared__ unsigned slot[NBIN];
  int tid = threadIdx.x;
  int b   = blockIdx.y;
  for (int i = tid; i < NBIN; i += 256) { hist[i] = 0u; slot[i] = 0u; }
  __syncthreads();
  const float F = par[34], ca = par[b*8+0], sa = par[b*8+1];
  const float* __restrict__ dpl = obs + ((size_t)b*NCH + 3)*NPIX;
  int base = blockIdx.x * 2048;
#pragma unroll
  for (int k = 0; k < 8; ++k) {
    int p = base + k*256 + tid;
    Geo g = geom(p, dpl[p], F, ca, sa);
    int bins[4];
    int n = pixel_bins(g, bins);
    for (int t = 0; t < n; ++t) atomicAdd(&hist[bins[t]], 1u);
  }
  __syncthreads();
  for (int i = tid; i < NBIN; i += 256) {
    unsigned h = hist[i];
    lbase[i] = h ? atomicAdd(&curs[b*NBIN + i], h) : 0u;
  }
  __syncthreads();
#pragma unroll
  for (int k = 0; k < 8; ++k) {
    int p = base + k*256 + tid;
    Geo g = geom(p, dpl[p], F, ca, sa);
    int bins[4];
    int n = pixel_bins(g, bins);
    for (int t = 0; t < n; ++t) {
      int bn = bins[t];
      unsigned sidx = atomicAdd(&slot[bn], 1u);
      list[lbase[bn] + sidx] = (unsigned)p;
    }
  }
}

// ---------------------------------------------------------------- splat + reduce (list-driven, u32 fixed-point LDS)
__global__ __launch_bounds__(1024) void k_splat2(const float* __restrict__ obs,
                                                 const float* __restrict__ semT,
                                                 const float* __restrict__ par,
                                                 const unsigned* __restrict__ offs,
                                                 const unsigned* __restrict__ counts,
                                                 const unsigned* __restrict__ list,
                                                 float* __restrict__ av,
                                                 float* __restrict__ avs) {
  __shared__ unsigned lds[CELLS * CELLF];
  const int tid = threadIdx.x;
  const int reg = blockIdx.x;
  const int b   = blockIdx.y;
  const int rx0 = (reg % NRX) * TX;
  const int ry0 = (reg / NRX) * TY;

  for (int i = tid; i < CELLS * CELLF; i += 1024) lds[i] = 0u;
  __syncthreads();

  const float F = par[34], ca = par[b*8+0], sa = par[b*8+1];
  const float* __restrict__ dpl = obs + ((size_t)b*NCH + 3)*NPIX;

  const unsigned bin   = (unsigned)b*NBIN + reg;
  const unsigned start = offs[bin];
  const unsigned n     = counts[bin];

  for (unsigned ii = tid; ii < n; ii += 1024) {
    int p = (int)list[start + ii];
    Geo g = geom(p, dpl[p], F, ca, sa);
    float px = g.px, py = g.py, pz = g.pz;
    float fx = floorf(px), fy = floorf(py), fz = floorf(pz);

    float wxa[2], wya[2], wza[2];
    int   ixa[2], iya[2], iza[2];
    bool  vx[2], vy[2], vz[2];
#pragma unroll
    for (int k = 0; k < 2; ++k) {
      float pv = fx + (float)k;
      bool sg = (pv > 0.0f) && (pv < 100.0f);
      wxa[k] = sg ? (1.0f - fabsf(px - pv)) : 0.0f;
      ixa[k] = (int)pv;
      vx[k]  = sg && (ixa[k] >= rx0) && (ixa[k] < rx0 + TX);

      pv = fy + (float)k;
      sg = (pv > 0.0f) && (pv < 100.0f);
      wya[k] = sg ? (1.0f - fabsf(py - pv)) : 0.0f;
      iya[k] = (int)pv;
      vy[k]  = sg && (iya[k] >= ry0) && (iya[k] < ry0 + TY);

      pv = fz + (float)k;
      sg = (pv > 0.0f) && (pv < 48.0f);
      wza[k] = sg ? (1.0f - fabsf(pz - pv)) : 0.0f;
      iza[k] = (int)pv;
      vz[k]  = sg;
    }

    bool needSem = false;
#pragma unroll
    for (int k = 0; k < 2; ++k)
      if (vz[k] && iza[k] >= 13 && iza[k] < 35 && wza[k] != 0.0f) needSem = true;

    float sem[16];
    if (needSem) {
      const float4* sp = (const float4*)(semT + ((size_t)b*NPIX + p)*16);
      float4 s0 = sp[0], s1 = sp[1], s2 = sp[2], s3 = sp[3];
      sem[0]=s0.x; sem[1]=s0.y; sem[2]=s0.z; sem[3]=s0.w;
      sem[4]=s1.x; sem[5]=s1.y; sem[6]=s1.z; sem[7]=s1.w;
      sem[8]=s2.x; sem[9]=s2.y; sem[10]=s2.z; sem[11]=s2.w;
      sem[12]=s3.x; sem[13]=s3.y; sem[14]=s3.z; sem[15]=s3.w;
    }

#pragma unroll
    for (int cx = 0; cx < 2; ++cx) {
      if (!vx[cx] || wxa[cx] == 0.0f) continue;
#pragma unroll
      for (int cy = 0; cy < 2; ++cy) {
        if (!vy[cy]) continue;
        float wxy = wxa[cx] * wya[cy];
        if (wxy == 0.0f) continue;
        unsigned* cellp = lds + (size_t)((ixa[cx]-rx0)*TY + (iya[cy]-ry0)) * CELLF;
#pragma unroll
        for (int cz = 0; cz < 2; ++cz) {
          if (!vz[cz]) continue;
          float wv = wxy * wza[cz];
          if (wv == 0.0f) continue;
          int zv = iza[cz];
          atomicAdd(cellp + zv, (unsigned)(wv*FPSCALE + 0.5f));
          if (zv >= 13 && zv < 35) {
            unsigned* p2 = cellp + 48 + (zv - 13)*16;
#pragma unroll
            for (int c = 0; c < 16; ++c)
              atomicAdd(p2 + c, (unsigned)(wv*sem[c]*FPSCALE + 0.5f));
          }
        }
      }
    }
  }
  __syncthreads();

  for (int it = tid; it < CELLS * 17; it += 1024) {
    int cell = it % CELLS;
    int ch   = it / CELLS;
    int lx = cell / TY, ly = cell % TY;
    int x = rx0 + lx, y = ry0 + ly;
    if (y >= 100) continue;
    size_t pxo = (size_t)y*VR + x;
    size_t ab  = (size_t)b*18*10000;
    const unsigned* cellp = lds + (size_t)cell * CELLF;
    if (ch == 0) {
      float all0 = 0.0f, ahp0 = 0.0f, asp0 = 0.0f;
#pragma unroll
      for (int z = 0; z < 48; ++z) {
        float v = rintf((float)cellp[z] * FPINV);
        all0 += v;
        if (z >= 13 && z < 35) ahp0 += v;
        if (z >= 20 && z < 25) asp0 += v;
      }
      av[ab + 0*10000 + pxo] = clip01(ahp0);
      av[ab + 1*10000 + pxo] = clip01(all0);
      avs[(size_t)b*10000 + pxo] = clip01(asp0);
    } else {
      int c = ch - 1;
      float acc = 0.0f;
      for (int z = 0; z < 22; ++z) acc += rintf((float)cellp[48 + z*16 + c] * FPINV);
      av[ab + (size_t)(2 + c)*10000 + pxo] = clip01(acc / 5.0f);
    }
  }
}

// ---------------------------------------------------------------- fast path: trivial stream over whole map
// Outside the heavy window: all taps are zero => out0=0, out1=out2=fmax(ml,0), kill=false.
__global__ __launch_bounds__(256) void k_fast(const float* __restrict__ maps_last,
                                              float* __restrict__ out0,
                                              float* __restrict__ out1,
                                              float* __restrict__ out2) {
  int p4 = blockIdx.x * 256 + threadIdx.x;   // float4 index within one batch
  int b  = blockIdx.y;
  const float4* __restrict__ ML4 = (const float4*)(maps_last + (size_t)b*NCH*MPX);
  float4* __restrict__ O04 = (float4*)(out0 + (size_t)b*NCH*MPX);
  float4* __restrict__ O14 = (float4*)(out1 + (size_t)b*NCH*MPX);
  float4* __restrict__ O24 = (float4*)(out2 + (size_t)b*NCH*MPX);
  const int s4 = MPX/4;
  const float4 z4 = make_float4(0.0f, 0.0f, 0.0f, 0.0f);
#pragma unroll
  for (int c = 0; c < NCH; ++c) {
    float4 m = ML4[c*s4 + p4];
    float4 r;
    r.x = fmaxf(m.x, 0.0f); r.y = fmaxf(m.y, 0.0f);
    r.z = fmaxf(m.z, 0.0f); r.w = fmaxf(m.w, 0.0f);
    O04[c*s4 + p4] = z4;
    O14[c*s4 + p4] = r;
    O24[c*s4 + p4] = r;
  }
}

// ---------------------------------------------------------------- heavy path: fused rot+trans+maxpool+merge on window
struct Nb { float wt, w00, w10, w01, w11; int o00, o10, o01, o11; };

__device__ __forceinline__ Nb rot_taps(int xi, int yi, float ct, float st, float wt) {
  Nb nb; nb.wt = 0.0f;
  nb.w00 = nb.w10 = nb.w01 = nb.w11 = 0.0f;
  nb.o00 = nb.o10 = nb.o01 = nb.o11 = 0;
  if (xi < 0 || xi >= MSZ || yi < 0 || yi >= MSZ) return nb;
  float gx = ((xi + 0.5f)*2.0f)/480.0f - 1.0f;
  float gy = ((yi + 0.5f)*2.0f)/480.0f - 1.0f;
  float u = gx*ct - gy*st;
  float v = gx*st + gy*ct;
  float xf = (u + 1.0f)*0.5f*479.0f;
  float yf = (v + 1.0f)*0.5f*479.0f;
  float x0f = floorf(xf), y0f = floorf(yf);
  int x0 = (int)x0f, y0 = (int)y0f;
  if (x0 < 189 || x0 > 289 || y0 < 239 || y0 > 339) return nb;
  float wx = xf - x0f, wy = yf - y0f;
  bool vx0 = (x0   >= 190) && (x0   < 290);
  bool vx1 = (x0+1 >= 190) && (x0+1 < 290);
  bool vy0 = (y0   >= 240) && (y0   < 340);
  bool vy1 = (y0+1 >= 240) && (y0+1 < 340);
  int base = (y0-240)*100 + (x0-190);
  bool v00 = vx0&&vy0, v10 = vx1&&vy0, v01 = vx0&&vy1, v11 = vx1&&vy1;
  nb.w00 = v00 ? (1.0f-wx)*(1.0f-wy) : 0.0f;  nb.o00 = v00 ? base       : 0;
  nb.w10 = v10 ? wx*(1.0f-wy)        : 0.0f;  nb.o10 = v10 ? base + 1   : 0;
  nb.w01 = v01 ? (1.0f-wx)*wy        : 0.0f;  nb.o01 = v01 ? base + 100 : 0;
  nb.w11 = v11 ? wx*wy               : 0.0f;  nb.o11 = v11 ? base + 101 : 0;
  nb.wt  = wt;
  return nb;
}

__device__ __forceinline__ bool trans_nbs(int w, int h, float sx, float sy,
                                          float ct, float st, Nb nb[4]) {
#pragma unroll
  for (int i = 0; i < 4; ++i) {
    nb[i].wt = 0.0f;
    nb[i].w00 = nb[i].w10 = nb[i].w01 = nb[i].w11 = 0.0f;
    nb[i].o00 = nb[i].o10 = nb[i].o01 = nb[i].o11 = 0;
  }
  float gx = ((w + 0.5f)*2.0f)/480.0f - 1.0f;
  float gy = ((h + 0.5f)*2.0f)/480.0f - 1.0f;
  float xf = ((gx + sx) + 1.0f)*0.5f*479.0f;
  float yf = ((gy + sy) + 1.0f)*0.5f*479.0f;
  float x0f = floorf(xf), y0f = floorf(yf);
  int x0 = (int)x0f, y0 = (int)y0f;
  if (x0 < -1 || x0 > 479 || y0 < -1 || y0 > 479) return false;
  float wx = xf - x0f, wy = yf - y0f;
  nb[0] = rot_taps(x0,   y0,   ct, st, (1.0f-wx)*(1.0f-wy));
  nb[1] = rot_taps(x0+1, y0,   ct, st, wx*(1.0f-wy));
  nb[2] = rot_taps(x0,   y0+1, ct, st, (1.0f-wx)*wy);
  nb[3] = rot_taps(x0+1, y0+1, ct, st, wx*wy);
  return (nb[0].wt!=0.0f)||(nb[1].wt!=0.0f)||(nb[2].wt!=0.0f)||(nb[3].wt!=0.0f);
}

__device__ __forceinline__ float eval_plane(const float* __restrict__ plane, const Nb nb[4]) {
  float t = 0.0f;
#pragma unroll
  for (int i = 0; i < 4; ++i) {
    if (nb[i].wt == 0.0f) continue;
    float r = plane[nb[i].o00]*nb[i].w00 + plane[nb[i].o10]*nb[i].w10
            + plane[nb[i].o01]*nb[i].w01 + plane[nb[i].o11]*nb[i].w11;
    t += nb[i].wt * r;
  }
  return t;
}

#define TILE 16
__global__ __launch_bounds__(256) void k_heavy(const float* __restrict__ av,
                                               const float* __restrict__ avs,
                                               const float* __restrict__ par,
                                               const float* __restrict__ maps_last,
                                               float* __restrict__ out0,
                                               float* __restrict__ out1,
                                               float* __restrict__ out2) {
  __shared__ float t0s[18][19];
  const int b   = blockIdx.y;
  const int wx0 = (int)par[40 + b*2];
  const int wy0 = (int)par[40 + b*2 + 1];
  const int tx0 = wx0 + (blockIdx.x % NT) * TILE;
  const int ty0 = wy0 + (blockIdx.x / NT) * TILE;
  const int lx  = threadIdx.x % TILE;
  const int ly  = threadIdx.x / TILE;

  const float ct = par[b*8+2], st = par[b*8+3];
  const float sx = par[b*8+4], sy = par[b*8+5];
  const float* __restrict__ av0 = av + (size_t)b*18*10000;

  // phase 1: fused ch0 for 18x18 halo
  for (int q = threadIdx.x; q < 18*18; q += 256) {
    int hy = q / 18, hx = q % 18;
    int h = ty0 + hy - 1, w = tx0 + hx - 1;
    float v;
    if (h < 0 || h >= MSZ || w < 0 || w >= MSZ) {
      v = -INFINITY;
    } else {
      Nb nb[4];
      v = trans_nbs(w, h, sx, sy, ct, st, nb) ? eval_plane(av0, nb) : 0.0f;
    }
    t0s[hy][hx] = v;
  }
  __syncthreads();

  // phase 2: own pixel
  const int h = ty0 + ly, w = tx0 + lx;
  const size_t pix = (size_t)h*MSZ + w;

  float mp = -INFINITY;
#pragma unroll
  for (int dy = 0; dy < 3; ++dy)
#pragma unroll
    for (int dx = 0; dx < 3; ++dx)
      mp = fmaxf(mp, t0s[ly+dy][lx+dx]);
  float t0 = t0s[ly+1][lx+1];

  Nb nb[4];
  bool hit = trans_nbs(w, h, sx, sy, ct, st, nb);

  float t[19];
  t[0] = t0;
  if (hit) {
#pragma unroll
    for (int s = 1; s < 18; ++s) t[s] = eval_plane(av0 + (size_t)s*10000, nb);
    t[18] = eval_plane(avs + (size_t)b*10000, nb);
  } else {
#pragma unroll
    for (int s = 1; s < 19; ++s) t[s] = 0.0f;
  }

  float t1v = t[1];
  bool eve0 = (par[b*8+6] != 0.0f);
  bool kill = ((t1v - mp) > 0.8f) && eve0;

  float sg = 1.0f;
  if (b == 0) {
    int sxi = (int)par[32], syi = (int)par[33];
    int di = h - (syi - 30);
    int dj = w - (sxi - 30);
    if (di >= 0 && di < 60 && dj >= 0 && dj < 60) {
      float aa = (float)di - 29.5f;
      float bb = (float)dj - 29.5f;
      sg = (aa*aa + bb*bb <= 900.0f) ? 1.0f : 0.0f;
    } else {
      sg = 0.0f;
    }
  }
  float tsv0 = t[18] * sg;
  float ts1  = t1v * sg;
  bool kill_s = ((ts1 - tsv0) > 0.8f) && eve0;

  const float* ML = maps_last + (size_t)b*NCH*MPX;
  float* O0 = out0 + (size_t)b*NCH*MPX;
  float* O1 = out1 + (size_t)b*NCH*MPX;
  float* O2 = out2 + (size_t)b*NCH*MPX;

#pragma unroll
  for (int c = 0; c < NCH; ++c) {
    float tv  = (c == 0) ? t0 : ((c == 1) ? t1v : ((c < 4) ? 0.0f : t[c - 2]));
    float tsv = (c == 0) ? tsv0 : ((c == 1) ? ts1 : tv);
    float ml  = ML[(size_t)c*MPX + pix];
    float mpv = fmaxf(ml, tv);
    float msv = fmaxf(ml, tsv);
    if (c == 0) {
      if (kill)   mpv = 0.0f;
      if (kill_s) msv = 0.0f;
    }
    O0[(size_t)c*MPX + pix] = tv;
    O1[(size_t)c*MPX + pix] = mpv;
    O2[(size_t)c*MPX + pix] = msv;
  }
}

// ---------------------------------------------------------------- launch
extern "C" void kernel_launch(void* const* d_in, const int* in_sizes, int n_in,
                              void* d_out, int out_size, void* d_ws, size_t ws_size,
                              hipStream_t stream) {
  (void)in_sizes; (void)n_in; (void)out_size; (void)ws_size;
  const float* obs        = (const float*)d_in[0];
  const float* pose_obs   = (const float*)d_in[1];
  const float* maps_last  = (const float*)d_in[2];
  const float* poses_last = (const float*)d_in[3];
  const float* eve        = (const float*)d_in[4];
  float* out = (float*)d_out;
  float* ws  = (float*)d_ws;

  float*    av     = ws + OFF_AV;
  float*    avs    = ws + OFF_AVS;
  float*    par    = ws + OFF_PAR;
  unsigned* counts = (unsigned*)(ws + OFF_COUNTS);
  unsigned* offs   = (unsigned*)(ws + OFF_OFFS);
  unsigned* curs   = (unsigned*)(ws + OFF_CURS);

  float* out0 = out;
  float* out1 = out + SEG;
  float* out2 = out + 2*SEG;
  float* outp = out + 3*SEG;

  // dead-segment scratch (consumed by k_splat2 before k_fast writes the outputs):
  float*    semT = out0;                        // spans out0 + head of out1
  unsigned* list = (unsigned*)(out + LIST_OFF); // inside out1 segment

  k_pose<<<1, 64, 0, stream>>>(pose_obs, poses_last, eve, par, outp, counts);
  {
    dim3 g(NPIX/2048, BS);
    k_prep<<<g, 256, 0, stream>>>(obs, par, counts, semT);
    k_scan<<<1, 1024, 0, stream>>>(counts, offs, curs);
    k_scatter<<<g, 256, 0, stream>>>(obs, par, curs, list);
  }
  {
    dim3 g(NBIN, BS);
    k_splat2<<<g, 1024, 0, stream>>>(obs, semT, par, offs, counts, list, av, avs);
  }
  {
    dim3 g(MPX/1024, BS);   // 225 x 4, float4-vectorized
    k_fast<<<g, 256, 0, stream>>>(maps_last, out0, out1, out2);
  }
  {
    dim3 g(NT*NT, BS);      // 121 tiles x 4, overwrites window region
    k_heavy<<<g, 256, 0, stream>>>(av, avs, par, maps_last, out0, out1, out2);
  }
}

// Round 9
// 269.993 us; speedup vs baseline: 1.1861x; 1.0678x over previous
//
#include <hip/hip_runtime.h>
#include <math.h>

#define BS 4
#define NCH 20
#define IMH 480
#define IMW 640
#define NPIX (IMH*IMW)           /* 307200 */
#define MSZ 480
#define MPX (MSZ*MSZ)            /* 230400 */
#define VR 100

#define TX 5
#define TY 8
#define NRX 20
#define NRY 13
#define NBIN (NRX*NRY)           /* 260 */
#define CELLS (TX*TY)            /* 40 */
#define CELLF 401                /* odd stride -> LDS bank spread; 64160 B -> 2 blocks/CU */

#define WND 176                  /* heavy-pass window (>= 152 worst-case) */
#define NT  11                   /* WND/16 */

#define FPSCALE 65536.0f
#define FPINV   (1.0f/65536.0f)
#define SEMSCALE 65535.0f
#define SEMINV   (1.0f/65535.0f)

typedef float    fx4  __attribute__((ext_vector_type(4)));
typedef unsigned ux4  __attribute__((ext_vector_type(4)));

static constexpr size_t SEG = (size_t)BS*NCH*MPX;            // 18,432,000 floats per output map
// semT: BS*NPIX*16 u16 = BS*NPIX*8 float-equivalents
static constexpr size_t SEMT_FLOATS = (size_t)BS*NPIX*8;     // 9,830,400
static constexpr size_t LIST_OFF    = SEMT_FLOATS;           // list follows semT in out0/out1 span
static_assert(LIST_OFF + 6000000 < 2*SEG, "semT+list must fit in out0+out1 segments");

static constexpr size_t OFF_AV     = 0;            // BS*18*10000
static constexpr size_t OFF_AVS    = 720000;       // BS*10000
static constexpr size_t OFF_PAR    = 1681600;      // 64 floats
static constexpr size_t OFF_COUNTS = 1681664;      // 1040 uints
static constexpr size_t OFF_OFFS   = 1682704;
static constexpr size_t OFF_CURS   = 1683744;

__device__ __forceinline__ float clip01(float v) { return fminf(fmaxf(v, 0.0f), 1.0f); }

struct Geo { float px, py, pz; };

__device__ __forceinline__ Geo geom(int p, float depth, float F, float ca, float sa) {
  int j = p % IMW;
  int i = p / IMW;
  float dF = depth * (1.0f / F);
  float X  = ((float)j - 319.5f) * dF;
  X += 250.0f;
  float gz = (float)(IMH - 1 - i);
  float Zc = (gz - 239.5f) * dF;
  float Y  = ca*depth - sa*Zc;
  float Z  = sa*depth + ca*Zc + 88.0f;
  float xs = (X/5.0f - 50.0f)/100.0f*2.0f;
  float ys = (Y/5.0f - 50.0f)/100.0f*2.0f;
  float zs = (Z/5.0f - 16.0f)/48.0f*2.0f;
  Geo g;
  g.px = xs*50.0f + 50.0f;
  g.py = ys*50.0f + 50.0f;
  g.pz = zs*24.0f + 24.0f;
  return g;
}

__device__ __forceinline__ int pixel_bins(Geo g, int bins[4]) {
  float fx = floorf(g.px), fy = floorf(g.py), fz = floorf(g.pz);
  float fx1 = fx + 1.0f, fy1 = fy + 1.0f, fz1 = fz + 1.0f;
  bool vx0 = (fx  > 0.0f) && (fx  < 100.0f);
  bool vx1 = (fx1 > 0.0f) && (fx1 < 100.0f);
  bool vy0 = (fy  > 0.0f) && (fy  < 100.0f);
  bool vy1 = (fy1 > 0.0f) && (fy1 < 100.0f);
  bool vz0 = (fz  > 0.0f) && (fz  < 48.0f);
  bool vz1 = (fz1 > 0.0f) && (fz1 < 48.0f);
  if (!((vx0||vx1) && (vy0||vy1) && (vz0||vz1))) return 0;
  int rxs[2]; int nx = 0;
  if (vx0) rxs[nx++] = (int)fx / TX;
  if (vx1) { int r = (int)fx1 / TX; if (!nx || r != rxs[0]) rxs[nx++] = r; }
  int rys[2]; int ny = 0;
  if (vy0) rys[ny++] = (int)fy / TY;
  if (vy1) { int r = (int)fy1 / TY; if (!ny || r != rys[0]) rys[ny++] = r; }
  int n = 0;
  for (int a = 0; a < ny; ++a)
    for (int c = 0; c < nx; ++c)
      bins[n++] = rys[a]*NRX + rxs[c];
  return n;
}

// ---------------------------------------------------------------- pose (+ zero bin counts + heavy window)
__global__ void k_pose(const float* __restrict__ pose_obs,
                       const float* __restrict__ poses_last,
                       const float* __restrict__ eve,
                       float* __restrict__ par,
                       float* __restrict__ out_poses,
                       unsigned* __restrict__ counts) {
  int b = threadIdx.x;
  for (int i = b; i < BS*NBIN; i += 64) counts[i] = 0u;
  if (b >= BS) return;
  const float R2Df = 57.29577951308232f;
  const float D2R  = 0.017453292519943295f;
  float pl0 = poses_last[b*3+0], pl1 = poses_last[b*3+1], pl2 = poses_last[b*3+2];
  float po0 = pose_obs[b*3+0],   po1 = pose_obs[b*3+1],   po2 = pose_obs[b*3+2];
  float r  = pl2 / R2Df;
  float sr = sinf(r), cr = cosf(r);
  float ny = pl1 + po0*sr + po1*cr;
  float nx = pl0 + po0*cr - po1*sr;
  float nt = pl2 + po2*R2Df;
  nt = fmodf(nt - 180.0f, 360.0f) + 180.0f;
  nt = fmodf(nt + 180.0f, 360.0f) - 180.0f;
  out_poses[b*3+0] = nx;
  out_poses[b*3+1] = ny;
  out_poses[b*3+2] = nt;
  float a = eve[b] * D2R;
  par[b*8+0] = cosf(a);
  par[b*8+1] = sinf(a);
  float t = (90.0f - nt) * D2R;
  float ct = cosf(t), st = sinf(t);
  float sxv = (240.0f - nx*100.0f/5.0f) / 240.0f;
  float syv = (240.0f - ny*100.0f/5.0f) / 240.0f;
  par[b*8+2] = ct;
  par[b*8+3] = st;
  par[b*8+4] = sxv;
  par[b*8+5] = syv;
  par[b*8+6] = (eve[b] == 0.0f) ? 1.0f : 0.0f;
  if (b == 0) {
    int sxi = (int)(nx * 100.0f / 5.0f);
    int syi = (int)(ny * 100.0f / 5.0f);
    sxi = min(max(sxi, 30), 449);
    syi = min(max(syi, 30), 449);
    par[32] = (float)sxi;
    par[33] = (float)syi;
    par[34] = (float)(320.0 / tan(39.5 * 0.017453292519943295));
  }
  // heavy-pass window: map AV rect corners through inverse rot, then inverse trans
  {
    const float u_lo = 189.0f/239.5f - 1.0f, u_hi = 290.0f/239.5f - 1.0f;
    const float v_lo = 239.0f/239.5f - 1.0f, v_hi = 340.0f/239.5f - 1.0f;
    float ximin = 1e9f, yimin = 1e9f;
#pragma unroll
    for (int k = 0; k < 4; ++k) {
      float uu = (k & 1) ? u_hi : u_lo;
      float vv = (k & 2) ? v_hi : v_lo;
      float gxc =  uu*ct + vv*st;       // inverse rotation
      float gyc = -uu*st + vv*ct;
      float xi = (gxc + 1.0f)*240.0f - 0.5f;
      float yi = (gyc + 1.0f)*240.0f - 0.5f;
      ximin = fminf(ximin, xi);
      yimin = fminf(yimin, yi);
    }
    float wmin = 240.0f*((ximin - 1.0f)/239.5f - sxv) - 0.5f;
    float hmin = 240.0f*((yimin - 1.0f)/239.5f - syv) - 0.5f;
    int wx0 = (int)floorf(wmin) - 3;
    int wy0 = (int)floorf(hmin) - 3;
    wx0 = min(max(wx0, 0), MSZ - WND);
    wy0 = min(max(wy0, 0), MSZ - WND);
    par[40 + b*2]     = (float)wx0;
    par[40 + b*2 + 1] = (float)wy0;
  }
}

// ---------------------------------------------------------------- prep: bin count + predicated u16 sem transpose
__global__ __launch_bounds__(256) void k_prep(const float* __restrict__ obs,
                                              const float* __restrict__ par,
                                              unsigned* __restrict__ counts,
                                              unsigned short* __restrict__ semT) {
  __shared__ unsigned hist[NBIN];
  int tid = threadIdx.x;
  int b   = blockIdx.y;
  for (int i = tid; i < NBIN; i += 256) hist[i] = 0u;
  __syncthreads();
  const float F = par[34], ca = par[b*8+0], sa = par[b*8+1];
  const float* __restrict__ dpl  = obs + ((size_t)b*NCH + 3)*NPIX;
  const float* __restrict__ semb = obs + ((size_t)b*NCH + 4)*NPIX;
  int base = blockIdx.x * 2048;
#pragma unroll
  for (int k = 0; k < 8; ++k) {
    int p = base + k*256 + tid;
    Geo g = geom(p, dpl[p], F, ca, sa);
    int bins[4];
    int n = pixel_bins(g, bins);
    for (int t = 0; t < n; ++t) atomicAdd(&hist[bins[t]], 1u);
    // write semT only if this pixel can ever contribute sem (superset of splat2's needSem)
    bool wantSem = false;
    if (n > 0) {
      float fz = floorf(g.pz);
#pragma unroll
      for (int kk = 0; kk < 2; ++kk) {
        float pv = fz + (float)kk;
        if (pv > 0.0f && pv < 48.0f) {
          int zv = (int)pv;
          if (zv >= 13 && zv < 35) wantSem = true;
        }
      }
    }
    if (wantSem) {
      unsigned u[8];
#pragma unroll
      for (int k2 = 0; k2 < 8; ++k2) {
        float s0 = semb[(size_t)(2*k2  )*NPIX + p];
        float s1 = semb[(size_t)(2*k2+1)*NPIX + p];
        unsigned q0 = (unsigned)(clip01(s0)*SEMSCALE + 0.5f);
        unsigned q1 = (unsigned)(clip01(s1)*SEMSCALE + 0.5f);
        u[k2] = q0 | (q1 << 16);
      }
      ux4* dst = (ux4*)(semT + ((size_t)b*NPIX + p)*16);
      ux4 v0 = {u[0], u[1], u[2], u[3]};
      ux4 v1 = {u[4], u[5], u[6], u[7]};
      __builtin_nontemporal_store(v0, dst);
      __builtin_nontemporal_store(v1, dst + 1);
    }
  }
  __syncthreads();
  for (int i = tid; i < NBIN; i += 256) {
    unsigned v = hist[i];
    if (v) atomicAdd(&counts[b*NBIN + i], v);
  }
}

// ---------------------------------------------------------------- exclusive scan of BS*NBIN=1040 counts
__global__ __launch_bounds__(1024) void k_scan(const unsigned* __restrict__ counts,
                                               unsigned* __restrict__ offs,
                                               unsigned* __restrict__ curs) {
  __shared__ unsigned s[1024];
  int t = threadIdx.x;
  const int n2 = BS*NBIN;
  unsigned a  = (2*t   < n2) ? counts[2*t]   : 0u;
  unsigned bb = (2*t+1 < n2) ? counts[2*t+1] : 0u;
  unsigned pr = a + bb;
  s[t] = pr;
  __syncthreads();
  for (int off = 1; off < 1024; off <<= 1) {
    unsigned v = (t >= off) ? s[t - off] : 0u;
    __syncthreads();
    s[t] += v;
    __syncthreads();
  }
  unsigned excl = s[t] - pr;
  if (2*t < n2)   { offs[2*t]   = excl;     curs[2*t]   = excl;     }
  if (2*t+1 < n2) { offs[2*t+1] = excl + a; curs[2*t+1] = excl + a; }
}

// ---------------------------------------------------------------- scatter pixel ids into bin lists
__global__ __launch_bounds__(256) void k_scatter(const float* __restrict__ obs,
                                                 const float* __restrict__ par,
                                                 unsigned* __restrict__ curs,
                                                 unsigned* __restrict__ list) {
  __shared__ unsigned hist[NBIN];
  __shared__ unsigned lbase[NBIN];
  __shared__ unsigned slot[NBIN];
  int tid = threadIdx.x;
  int b   = blockIdx.y;
  for (int i = tid; i < NBIN; i += 256) { hist[i] = 0u; slot[i] = 0u; }
  __syncthreads();
  const float F = par[34], ca = par[b*8+0], sa = par[b*8+1];
  const float* __restrict__ dpl = obs + ((size_t)b*NCH + 3)*NPIX;
  int base = blockIdx.x * 2048;
#pragma unroll
  for (int k = 0; k < 8; ++k) {
    int p = base + k*256 + tid;
    Geo g = geom(p, dpl[p], F, ca, sa);
    int bins[4];
    int n = pixel_bins(g, bins);
    for (int t = 0; t < n; ++t) atomicAdd(&hist[bins[t]], 1u);
  }
  __syncthreads();
  for (int i = tid; i < NBIN; i += 256) {
    unsigned h = hist[i];
    lbase[i] = h ? atomicAdd(&curs[b*NBIN + i], h) : 0u;
  }
  __syncthreads();
#pragma unroll
  for (int k = 0; k < 8; ++k) {
    int p = base + k*256 + tid;
    Geo g = geom(p, dpl[p], F, ca, sa);
    int bins[4];
    int n = pixel_bins(g, bins);
    for (int t = 0; t < n; ++t) {
      int bn = bins[t];
      unsigned sidx = atomicAdd(&slot[bn], 1u);
      list[lbase[bn] + sidx] = (unsigned)p;
    }
  }
}

// ---------------------------------------------------------------- splat + reduce (list-driven, u32 fixed-point LDS)
__global__ __launch_bounds__(1024) void k_splat2(const float* __restrict__ obs,
                                                 const unsigned short* __restrict__ semT,
                                                 const float* __restrict__ par,
                                                 const unsigned* __restrict__ offs,
                                                 const unsigned* __restrict__ counts,
                                                 const unsigned* __restrict__ list,
                                                 float* __restrict__ av,
                                                 float* __restrict__ avs) {
  __shared__ unsigned lds[CELLS * CELLF];
  const int tid = threadIdx.x;
  const int reg = blockIdx.x;
  const int b   = blockIdx.y;
  const int rx0 = (reg % NRX) * TX;
  const int ry0 = (reg / NRX) * TY;

  for (int i = tid; i < CELLS * CELLF; i += 1024) lds[i] = 0u;
  __syncthreads();

  const float F = par[34], ca = par[b*8+0], sa = par[b*8+1];
  const float* __restrict__ dpl = obs + ((size_t)b*NCH + 3)*NPIX;

  const unsigned bin   = (unsigned)b*NBIN + reg;
  const unsigned start = offs[bin];
  const unsigned n     = counts[bin];

  for (unsigned ii = tid; ii < n; ii += 1024) {
    int p = (int)list[start + ii];
    Geo g = geom(p, dpl[p], F, ca, sa);
    float px = g.px, py = g.py, pz = g.pz;
    float fx = floorf(px), fy = floorf(py), fz = floorf(pz);

    float wxa[2], wya[2], wza[2];
    int   ixa[2], iya[2], iza[2];
    bool  vx[2], vy[2], vz[2];
#pragma unroll
    for (int k = 0; k < 2; ++k) {
      float pv = fx + (float)k;
      bool sg = (pv > 0.0f) && (pv < 100.0f);
      wxa[k] = sg ? (1.0f - fabsf(px - pv)) : 0.0f;
      ixa[k] = (int)pv;
      vx[k]  = sg && (ixa[k] >= rx0) && (ixa[k] < rx0 + TX);

      pv = fy + (float)k;
      sg = (pv > 0.0f) && (pv < 100.0f);
      wya[k] = sg ? (1.0f - fabsf(py - pv)) : 0.0f;
      iya[k] = (int)pv;
      vy[k]  = sg && (iya[k] >= ry0) && (iya[k] < ry0 + TY);

      pv = fz + (float)k;
      sg = (pv > 0.0f) && (pv < 48.0f);
      wza[k] = sg ? (1.0f - fabsf(pz - pv)) : 0.0f;
      iza[k] = (int)pv;
      vz[k]  = sg;
    }

    bool needSem = false;
#pragma unroll
    for (int k = 0; k < 2; ++k)
      if (vz[k] && iza[k] >= 13 && iza[k] < 35 && wza[k] != 0.0f) needSem = true;

    float sem[16];
    if (needSem) {
      const ux4* sp = (const ux4*)(semT + ((size_t)b*NPIX + p)*16);
      ux4 a4 = sp[0], b4 = sp[1];
      sem[0]  = (float)(a4.x & 0xffffu); sem[1]  = (float)(a4.x >> 16);
      sem[2]  = (float)(a4.y & 0xffffu); sem[3]  = (float)(a4.y >> 16);
      sem[4]  = (float)(a4.z & 0xffffu); sem[5]  = (float)(a4.z >> 16);
      sem[6]  = (float)(a4.w & 0xffffu); sem[7]  = (float)(a4.w >> 16);
      sem[8]  = (float)(b4.x & 0xffffu); sem[9]  = (float)(b4.x >> 16);
      sem[10] = (float)(b4.y & 0xffffu); sem[11] = (float)(b4.y >> 16);
      sem[12] = (float)(b4.z & 0xffffu); sem[13] = (float)(b4.z >> 16);
      sem[14] = (float)(b4.w & 0xffffu); sem[15] = (float)(b4.w >> 16);
    }

#pragma unroll
    for (int cx = 0; cx < 2; ++cx) {
      if (!vx[cx] || wxa[cx] == 0.0f) continue;
#pragma unroll
      for (int cy = 0; cy < 2; ++cy) {
        if (!vy[cy]) continue;
        float wxy = wxa[cx] * wya[cy];
        if (wxy == 0.0f) continue;
        unsigned* cellp = lds + (size_t)((ixa[cx]-rx0)*TY + (iya[cy]-ry0)) * CELLF;
#pragma unroll
        for (int cz = 0; cz < 2; ++cz) {
          if (!vz[cz]) continue;
          float wv = wxy * wza[cz];
          if (wv == 0.0f) continue;
          int zv = iza[cz];
          atomicAdd(cellp + zv, (unsigned)(wv*FPSCALE + 0.5f));   // ch0, scale 2^16
          if (zv >= 13 && zv < 35) {
            unsigned* p2 = cellp + 48 + (zv - 13)*16;
#pragma unroll
            for (int c = 0; c < 16; ++c)
              atomicAdd(p2 + c, (unsigned)(wv*sem[c] + 0.5f));    // sem already x65535
          }
        }
      }
    }
  }
  __syncthreads();

  for (int it = tid; it < CELLS * 17; it += 1024) {
    int cell = it % CELLS;
    int ch   = it / CELLS;
    int lx = cell / TY, ly = cell % TY;
    int x = rx0 + lx, y = ry0 + ly;
    if (y >= 100) continue;
    size_t pxo = (size_t)y*VR + x;
    size_t ab  = (size_t)b*18*10000;
    const unsigned* cellp = lds + (size_t)cell * CELLF;
    if (ch == 0) {
      float all0 = 0.0f, ahp0 = 0.0f, asp0 = 0.0f;
#pragma unroll
      for (int z = 0; z < 48; ++z) {
        float v = rintf((float)cellp[z] * FPINV);
        all0 += v;
        if (z >= 13 && z < 35) ahp0 += v;
        if (z >= 20 && z < 25) asp0 += v;
      }
      av[ab + 0*10000 + pxo] = clip01(ahp0);
      av[ab + 1*10000 + pxo] = clip01(all0);
      avs[(size_t)b*10000 + pxo] = clip01(asp0);
    } else {
      int c = ch - 1;
      float acc = 0.0f;
      for (int z = 0; z < 22; ++z) acc += rintf((float)cellp[48 + z*16 + c] * SEMINV);
      av[ab + (size_t)(2 + c)*10000 + pxo] = clip01(acc / 5.0f);
    }
  }
}

// ---------------------------------------------------------------- fast path: flat nontemporal stream
// Outside the heavy window: out0=0, out1=out2=fmax(ml,0). (Window overwritten by k_heavy.)
__global__ __launch_bounds__(256) void k_fast(const float* __restrict__ maps_last,
                                              float* __restrict__ out0,
                                              float* __restrict__ out1,
                                              float* __restrict__ out2) {
  size_t i = (size_t)blockIdx.x * 256 + threadIdx.x;   // fx4 index over SEG/4
  const fx4* __restrict__ m4 = (const fx4*)maps_last;
  fx4 m = __builtin_nontemporal_load(m4 + i);
  fx4 r;
  r.x = fmaxf(m.x, 0.0f); r.y = fmaxf(m.y, 0.0f);
  r.z = fmaxf(m.z, 0.0f); r.w = fmaxf(m.w, 0.0f);
  fx4 z4 = {0.0f, 0.0f, 0.0f, 0.0f};
  __builtin_nontemporal_store(z4, (fx4*)out0 + i);
  __builtin_nontemporal_store(r,  (fx4*)out1 + i);
  __builtin_nontemporal_store(r,  (fx4*)out2 + i);
}

// ---------------------------------------------------------------- heavy path: fused rot+trans+maxpool+merge on window
struct Nb { float wt, w00, w10, w01, w11; int o00, o10, o01, o11; };

__device__ __forceinline__ Nb rot_taps(int xi, int yi, float ct, float st, float wt) {
  Nb nb; nb.wt = 0.0f;
  nb.w00 = nb.w10 = nb.w01 = nb.w11 = 0.0f;
  nb.o00 = nb.o10 = nb.o01 = nb.o11 = 0;
  if (xi < 0 || xi >= MSZ || yi < 0 || yi >= MSZ) return nb;
  float gx = ((xi + 0.5f)*2.0f)/480.0f - 1.0f;
  float gy = ((yi + 0.5f)*2.0f)/480.0f - 1.0f;
  float u = gx*ct - gy*st;
  float v = gx*st + gy*ct;
  float xf = (u + 1.0f)*0.5f*479.0f;
  float yf = (v + 1.0f)*0.5f*479.0f;
  float x0f = floorf(xf), y0f = floorf(yf);
  int x0 = (int)x0f, y0 = (int)y0f;
  if (x0 < 189 || x0 > 289 || y0 < 239 || y0 > 339) return nb;
  float wx = xf - x0f, wy = yf - y0f;
  bool vx0 = (x0   >= 190) && (x0   < 290);
  bool vx1 = (x0+1 >= 190) && (x0+1 < 290);
  bool vy0 = (y0   >= 240) && (y0   < 340);
  bool vy1 = (y0+1 >= 240) && (y0+1 < 340);
  int base = (y0-240)*100 + (x0-190);
  bool v00 = vx0&&vy0, v10 = vx1&&vy0, v01 = vx0&&vy1, v11 = vx1&&vy1;
  nb.w00 = v00 ? (1.0f-wx)*(1.0f-wy) : 0.0f;  nb.o00 = v00 ? base       : 0;
  nb.w10 = v10 ? wx*(1.0f-wy)        : 0.0f;  nb.o10 = v10 ? base + 1   : 0;
  nb.w01 = v01 ? (1.0f-wx)*wy        : 0.0f;  nb.o01 = v01 ? base + 100 : 0;
  nb.w11 = v11 ? wx*wy               : 0.0f;  nb.o11 = v11 ? base + 101 : 0;
  nb.wt  = wt;
  return nb;
}

__device__ __forceinline__ bool trans_nbs(int w, int h, float sx, float sy,
                                          float ct, float st, Nb nb[4]) {
#pragma unroll
  for (int i = 0; i < 4; ++i) {
    nb[i].wt = 0.0f;
    nb[i].w00 = nb[i].w10 = nb[i].w01 = nb[i].w11 = 0.0f;
    nb[i].o00 = nb[i].o10 = nb[i].o01 = nb[i].o11 = 0;
  }
  float gx = ((w + 0.5f)*2.0f)/480.0f - 1.0f;
  float gy = ((h + 0.5f)*2.0f)/480.0f - 1.0f;
  float xf = ((gx + sx) + 1.0f)*0.5f*479.0f;
  float yf = ((gy + sy) + 1.0f)*0.5f*479.0f;
  float x0f = floorf(xf), y0f = floorf(yf);
  int x0 = (int)x0f, y0 = (int)y0f;
  if (x0 < -1 || x0 > 479 || y0 < -1 || y0 > 479) return false;
  float wx = xf - x0f, wy = yf - y0f;
  nb[0] = rot_taps(x0,   y0,   ct, st, (1.0f-wx)*(1.0f-wy));
  nb[1] = rot_taps(x0+1, y0,   ct, st, wx*(1.0f-wy));
  nb[2] = rot_taps(x0,   y0+1, ct, st, (1.0f-wx)*wy);
  nb[3] = rot_taps(x0+1, y0+1, ct, st, wx*wy);
  return (nb[0].wt!=0.0f)||(nb[1].wt!=0.0f)||(nb[2].wt!=0.0f)||(nb[3].wt!=0.0f);
}

__device__ __forceinline__ float eval_plane(const float* __restrict__ plane, const Nb nb[4]) {
  float t = 0.0f;
#pragma unroll
  for (int i = 0; i < 4; ++i) {
    if (nb[i].wt == 0.0f) continue;
    float r = plane[nb[i].o00]*nb[i].w00 + plane[nb[i].o10]*nb[i].w10
            + plane[nb[i].o01]*nb[i].w01 + plane[nb[i].o11]*nb[i].w11;
    t += nb[i].wt * r;
  }
  return t;
}

#define TILE 16
__global__ __launch_bounds__(256) void k_heavy(const float* __restrict__ av,
                                               const float* __restrict__ avs,
                                               const float* __restrict__ par,
                                               const float* __restrict__ maps_last,
                                               float* __restrict__ out0,
                                               float* __restrict__ out1,
                                               float* __restrict__ out2) {
  __shared__ float t0s[18][19];
  const int b   = blockIdx.y;
  const int wx0 = (int)par[40 + b*2];
  const int wy0 = (int)par[40 + b*2 + 1];
  const int tx0 = wx0 + (blockIdx.x % NT) * TILE;
  const int ty0 = wy0 + (blockIdx.x / NT) * TILE;
  const int lx  = threadIdx.x % TILE;
  const int ly  = threadIdx.x / TILE;

  const float ct = par[b*8+2], st = par[b*8+3];
  const float sx = par[b*8+4], sy = par[b*8+5];
  const float* __restrict__ av0 = av + (size_t)b*18*10000;

  for (int q = threadIdx.x; q < 18*18; q += 256) {
    int hy = q / 18, hx = q % 18;
    int h = ty0 + hy - 1, w = tx0 + hx - 1;
    float v;
    if (h < 0 || h >= MSZ || w < 0 || w >= MSZ) {
      v = -INFINITY;
    } else {
      Nb nb[4];
      v = trans_nbs(w, h, sx, sy, ct, st, nb) ? eval_plane(av0, nb) : 0.0f;
    }
    t0s[hy][hx] = v;
  }
  __syncthreads();

  const int h = ty0 + ly, w = tx0 + lx;
  const size_t pix = (size_t)h*MSZ + w;

  float mp = -INFINITY;
#pragma unroll
  for (int dy = 0; dy < 3; ++dy)
#pragma unroll
    for (int dx = 0; dx < 3; ++dx)
      mp = fmaxf(mp, t0s[ly+dy][lx+dx]);
  float t0 = t0s[ly+1][lx+1];

  Nb nb[4];
  bool hit = trans_nbs(w, h, sx, sy, ct, st, nb);

  float t[19];
  t[0] = t0;
  if (hit) {
#pragma unroll
    for (int s = 1; s < 18; ++s) t[s] = eval_plane(av0 + (size_t)s*10000, nb);
    t[18] = eval_plane(avs + (size_t)b*10000, nb);
  } else {
#pragma unroll
    for (int s = 1; s < 19; ++s) t[s] = 0.0f;
  }

  float t1v = t[1];
  bool eve0 = (par[b*8+6] != 0.0f);
  bool kill = ((t1v - mp) > 0.8f) && eve0;

  float sg = 1.0f;
  if (b == 0) {
    int sxi = (int)par[32], syi = (int)par[33];
    int di = h - (syi - 30);
    int dj = w - (sxi - 30);
    if (di >= 0 && di < 60 && dj >= 0 && dj < 60) {
      float aa = (float)di - 29.5f;
      float bb = (float)dj - 29.5f;
      sg = (aa*aa + bb*bb <= 900.0f) ? 1.0f : 0.0f;
    } else {
      sg = 0.0f;
    }
  }
  float tsv0 = t[18] * sg;
  float ts1  = t1v * sg;
  bool kill_s = ((ts1 - tsv0) > 0.8f) && eve0;

  const float* ML = maps_last + (size_t)b*NCH*MPX;
  float* O0 = out0 + (size_t)b*NCH*MPX;
  float* O1 = out1 + (size_t)b*NCH*MPX;
  float* O2 = out2 + (size_t)b*NCH*MPX;

#pragma unroll
  for (int c = 0; c < NCH; ++c) {
    float tv  = (c == 0) ? t0 : ((c == 1) ? t1v : ((c < 4) ? 0.0f : t[c - 2]));
    float tsv = (c == 0) ? tsv0 : ((c == 1) ? ts1 : tv);
    float ml  = ML[(size_t)c*MPX + pix];
    float mpv = fmaxf(ml, tv);
    float msv = fmaxf(ml, tsv);
    if (c == 0) {
      if (kill)   mpv = 0.0f;
      if (kill_s) msv = 0.0f;
    }
    O0[(size_t)c*MPX + pix] = tv;
    O1[(size_t)c*MPX + pix] = mpv;
    O2[(size_t)c*MPX + pix] = msv;
  }
}

// ---------------------------------------------------------------- launch
extern "C" void kernel_launch(void* const* d_in, const int* in_sizes, int n_in,
                              void* d_out, int out_size, void* d_ws, size_t ws_size,
                              hipStream_t stream) {
  (void)in_sizes; (void)n_in; (void)out_size; (void)ws_size;
  const float* obs        = (const float*)d_in[0];
  const float* pose_obs   = (const float*)d_in[1];
  const float* maps_last  = (const float*)d_in[2];
  const float* poses_last = (const float*)d_in[3];
  const float* eve        = (const float*)d_in[4];
  float* out = (float*)d_out;
  float* ws  = (float*)d_ws;

  float*    av     = ws + OFF_AV;
  float*    avs    = ws + OFF_AVS;
  float*    par    = ws + OFF_PAR;
  unsigned* counts = (unsigned*)(ws + OFF_COUNTS);
  unsigned* offs   = (unsigned*)(ws + OFF_OFFS);
  unsigned* curs   = (unsigned*)(ws + OFF_CURS);

  float* out0 = out;
  float* out2 = out + 2*SEG;
  float* outp = out + 3*SEG;

  // dead-segment scratch (consumed by k_splat2 before k_fast writes the outputs):
  unsigned short* semT = (unsigned short*)out0;      // BS*NPIX*16 u16, within out0
  unsigned*       list = (unsigned*)(out + LIST_OFF);// follows semT, within out0/out1 span

  k_pose<<<1, 64, 0, stream>>>(pose_obs, poses_last, eve, par, outp, counts);
  {
    dim3 g(NPIX/2048, BS);
    k_prep<<<g, 256, 0, stream>>>(obs, par, counts, semT);
    k_scan<<<1, 1024, 0, stream>>>(counts, offs, curs);
    k_scatter<<<g, 256, 0, stream>>>(obs, par, curs, list);
  }
  {
    dim3 g(NBIN, BS);
    k_splat2<<<g, 1024, 0, stream>>>(obs, semT, par, offs, counts, list, av, avs);
  }
  {
    // flat stream over all 3 output maps: SEG/4 fx4s, 256/block
    k_fast<<<SEG/4/256, 256, 0, stream>>>(maps_last, out0, out + SEG, out2);
  }
  {
    dim3 g(NT*NT, BS);      // 121 tiles x 4, overwrites window region
    k_heavy<<<g, 256, 0, stream>>>(av, avs, par, maps_last, out0, out + SEG, out2);
  }
}